// Round 6
// baseline (222.968 us; speedup 1.0000x reference)
//
#include <hip/hip_runtime.h>
#include <math.h>

#define N_NODES 20000
#define N_PAD64 20032          // N_NODES rounded up to 64 (GEMM M-tile)
#define N_EDGES 320000
#define IN_CH 512
#define HEADS 4
#define OUT_CH 128
#define HC 512                 // HEADS*OUT_CH
#define NEG_SLOPE 0.2f

#define GEMM_BM 64
#define GEMM_BK 32
#define GRID_M 313             // N_PAD64/64

// fused-kernel block partitions
#define CVW_BLOCKS 64          // (IN_CH/64)*(HC/64)
#define CNT_BLOCKS 1250        // N_EDGES/256

typedef __attribute__((ext_vector_type(8))) short short8;
typedef __attribute__((ext_vector_type(4))) float float4v;

// ---------------- edge-index dtype detection (inline, deterministic) ----------------
__device__ __forceinline__ int detect_is64(const int* __restrict__ ei32) {
    int is64 = 1;
    #pragma unroll
    for (int i = 0; i < 32; i++) is64 &= (ei32[2 * i + 1] == 0);
    return is64;
}

__device__ __forceinline__ int edge_at(const void* ei, int is64, long long idx) {
    return is64 ? (int)((const long long*)ei)[idx] : ((const int*)ei)[idx];
}

__device__ __forceinline__ unsigned short f2bf(float f) {
    union { float f; unsigned u; } v; v.f = f;
    unsigned r = v.u + 0x7fffu + ((v.u >> 16) & 1u);   // RNE
    return (unsigned short)(r >> 16);
}

// decode 8 packed bf16 (uint4) -> 8 floats
__device__ __forceinline__ void bf8_decode(uint4 r, float* f) {
    f[0] = __uint_as_float(r.x << 16); f[1] = __uint_as_float(r.x & 0xffff0000u);
    f[2] = __uint_as_float(r.y << 16); f[3] = __uint_as_float(r.y & 0xffff0000u);
    f[4] = __uint_as_float(r.z << 16); f[5] = __uint_as_float(r.z & 0xffff0000u);
    f[6] = __uint_as_float(r.w << 16); f[7] = __uint_as_float(r.w & 0xffff0000u);
}

__device__ __forceinline__ float leaky(float t) { return t > 0.f ? t : NEG_SLOPE * t; }

__device__ __forceinline__ float sel_head(float4 w, int hd) {
    float lo = (hd & 1) ? w.y : w.x;
    float hi = (hd & 1) ? w.w : w.z;
    return (hd & 2) ? hi : lo;
}

// ---------------- K1: fused convert_w(transpose) + count ----------------
__global__ __launch_bounds__(256) void fusedA_kernel(const float* __restrict__ W,
                                                     unsigned short* __restrict__ Wt,
                                                     const void* __restrict__ ei,
                                                     int* __restrict__ counts) {
    __shared__ float tile[64][65];
    int b = blockIdx.x;
    if (b < CVW_BLOCKS) {
        int k0 = (b & 7) * 64, n0 = (b >> 3) * 64;
        int t = threadIdx.x, r = t >> 6, c = t & 63;
        for (int rr = r; rr < 64; rr += 4)
            tile[rr][c] = W[(size_t)(k0 + rr) * HC + n0 + c];
        __syncthreads();
        for (int rr = r; rr < 64; rr += 4)
            Wt[(size_t)(n0 + rr) * IN_CH + k0 + c] = f2bf(tile[c][rr]);
    } else {
        int is64 = detect_is64((const int*)ei);
        int e = (b - CVW_BLOCKS) * 256 + threadIdx.x;
        if (e < N_EDGES) {
            int dst = edge_at(ei, is64, (long long)N_EDGES + e);
            atomicAdd(&counts[dst], 1);
        }
    }
}

// ---------------- K2: bf16 MFMA GEMM (full-N blocks) + fused attention halves ----
// BM=64, BN=512(all), BK=32, 512 threads (8 waves; wave wv owns cols wv*64..+63).
// A (fp32 x) converted to bf16 in-register during staging; B staged via
// global_load_lds (Wt is 512KB, L2-resident). Epilogue computes
// a_s[n,h]=sum_c xl*att_s (block owns full rows -> no atomics).
__global__ __launch_bounds__(512) void gemm_kernel(const float* __restrict__ x,
                                                   const unsigned short* __restrict__ Wt,
                                                   unsigned short* __restrict__ Cb,
                                                   const float* __restrict__ att_s_g,
                                                   const float* __restrict__ att_d_g,
                                                   float* __restrict__ a_s,
                                                   float* __restrict__ a_d) {
    __shared__ __align__(16) unsigned short As[GEMM_BM * GEMM_BK];   // 4 KB
    __shared__ __align__(16) unsigned short Bs[HC * GEMM_BK];        // 32 KB
    __shared__ float red_s[8][GEMM_BM];                              // 2 KB
    __shared__ float red_d[8][GEMM_BM];                              // 2 KB
    const int bm = blockIdx.x * GEMM_BM;
    const int t = threadIdx.x;
    const int wv = t >> 6, lane = t & 63;
    const int lm = lane & 15, lk = lane >> 4;

    float4v acc[4][4];   // [i: M 16-tiles][j: N 16-tiles within wave's 64-col slice]
    #pragma unroll
    for (int i = 0; i < 4; i++)
        #pragma unroll
        for (int j = 0; j < 4; j++) acc[i][j] = (float4v){0.f, 0.f, 0.f, 0.f};

    const int arow = t >> 3;         // 0..63
    const int akof = (t & 7) * 4;    // fp32 element offset (float4)
    const int agrow = bm + arow;

    for (int k0 = 0; k0 < IN_CH; k0 += GEMM_BK) {
        __syncthreads();   // previous iteration's ds_reads complete
        // A: fp32 load + convert + ds_write (8 B, contiguous by thread)
        float4 av = make_float4(0.f, 0.f, 0.f, 0.f);
        if (agrow < N_NODES) av = *(const float4*)&x[(size_t)agrow * IN_CH + k0 + akof];
        uint2 ap;
        ap.x = (unsigned)f2bf(av.x) | ((unsigned)f2bf(av.y) << 16);
        ap.y = (unsigned)f2bf(av.z) | ((unsigned)f2bf(av.w) << 16);
        *(uint2*)&As[arow * GEMM_BK + akof] = ap;
        // B: global_load_lds 16B x4 (chunk c = q*512+t -> LDS byte addr c*16, linear)
        #pragma unroll
        for (int q = 0; q < 4; q++) {
            int c = q * 512 + t;
            int n = c >> 2, k8 = (c & 3) * 8;
            const unsigned short* gB = Wt + (size_t)n * IN_CH + k0 + k8;
            __builtin_amdgcn_global_load_lds((const __attribute__((address_space(1))) void*)gB,
                                             (__attribute__((address_space(3))) void*)&Bs[n * GEMM_BK + k8], 16, 0, 0);
        }
        __syncthreads();   // drains lgkm + vmcnt

        short8 af[4], bf[4];
        #pragma unroll
        for (int i = 0; i < 4; i++)
            af[i] = *(const short8*)&As[(i * 16 + lm) * GEMM_BK + lk * 8];
        #pragma unroll
        for (int j = 0; j < 4; j++)
            bf[j] = *(const short8*)&Bs[(wv * 64 + j * 16 + lm) * GEMM_BK + lk * 8];
        #pragma unroll
        for (int i = 0; i < 4; i++)
            #pragma unroll
            for (int j = 0; j < 4; j++)
                acc[i][j] = __builtin_amdgcn_mfma_f32_16x16x32_bf16(af[i], bf[j], acc[i][j], 0, 0, 0);
    }

    // ---- C write (C/D layout: col = lane&15, row = (lane>>4)*4 + reg) ----
    #pragma unroll
    for (int i = 0; i < 4; i++) {
        #pragma unroll
        for (int r = 0; r < 4; r++) {
            int row = bm + i * 16 + lk * 4 + r;
            if (row < N_NODES) {
                #pragma unroll
                for (int j = 0; j < 4; j++) {
                    int col = wv * 64 + j * 16 + lm;
                    Cb[(size_t)row * HC + col] = f2bf(acc[i][j][r]);
                }
            }
        }
    }

    // ---- fused attention halves: a = sum_c xl[row][c] * att[c] ----
    float asv[4], adv[4];
    #pragma unroll
    for (int j = 0; j < 4; j++) {
        int col = wv * 64 + j * 16 + lm;
        asv[j] = att_s_g[col];
        adv[j] = att_d_g[col];
    }
    #pragma unroll
    for (int i = 0; i < 4; i++) {
        #pragma unroll
        for (int r = 0; r < 4; r++) {
            float s = acc[i][0][r] * asv[0] + acc[i][1][r] * asv[1]
                    + acc[i][2][r] * asv[2] + acc[i][3][r] * asv[3];
            float d = acc[i][0][r] * adv[0] + acc[i][1][r] * adv[1]
                    + acc[i][2][r] * adv[2] + acc[i][3][r] * adv[3];
            #pragma unroll
            for (int off = 1; off < 16; off <<= 1) {   // reduce over lm (same lk group)
                s += __shfl_xor(s, off, 64);
                d += __shfl_xor(d, off, 64);
            }
            if (lm == 0) {
                red_s[wv][i * 16 + lk * 4 + r] = s;
                red_d[wv][i * 16 + lk * 4 + r] = d;
            }
        }
    }
    __syncthreads();
    if (t < 256) {
        int row = t & 63, h = t >> 6;   // wave pair 2h,2h+1 covered head h's 128 cols
        int grow = bm + row;
        if (grow < N_NODES) {
            a_s[grow * 4 + h] = red_s[2 * h][row] + red_s[2 * h + 1][row];
            a_d[grow * 4 + h] = red_d[2 * h][row] + red_d[2 * h + 1][row];
        }
    }
}

// ---------------- K3: chunked block scan: counts -> exclusive offsets ----------------
__global__ __launch_bounds__(1024) void scan_kernel(const int* __restrict__ counts,
                                                    int* __restrict__ offsets) {
    const int CHUNK = 20;                 // 1024*20 = 20480 >= N_NODES
    int tid = threadIdx.x;
    int base = tid * CHUNK;
    int c[CHUNK];
    #pragma unroll
    for (int k = 0; k < CHUNK; k++) {
        int i = base + k;
        c[k] = (i < N_NODES) ? counts[i] : 0;
    }
    int pre[CHUNK];
    int sum = 0;
    #pragma unroll
    for (int k = 0; k < CHUNK; k++) { pre[k] = sum; sum += c[k]; }

    int lane = tid & 63, wv = tid >> 6;
    int s = sum;
    #pragma unroll
    for (int off = 1; off < 64; off <<= 1) {
        int u = __shfl_up(s, off, 64);
        if (lane >= off) s += u;
    }
    __shared__ int wsum[16];
    if (lane == 63) wsum[wv] = s;
    __syncthreads();
    if (tid < 16) {
        int u = wsum[tid];
        #pragma unroll
        for (int off = 1; off < 16; off <<= 1) {
            int w = __shfl_up(u, off, 64);
            if (tid >= off) u += w;
        }
        wsum[tid] = u;
    }
    __syncthreads();
    int wbase = (wv == 0) ? 0 : wsum[wv - 1];
    int excl = wbase + s - sum;
    #pragma unroll
    for (int k = 0; k < CHUNK; k++) {
        int i = base + k;
        if (i < N_NODES) offsets[i] = excl + pre[k];
    }
    if (tid == 1023) offsets[N_NODES] = wbase + s;
}

// ---------------- K4: scatter + per-edge weights ----------------
__global__ __launch_bounds__(256) void scatterw_kernel(const void* __restrict__ ei,
                                                       const int* __restrict__ offsets,
                                                       int* __restrict__ cursor,
                                                       int* __restrict__ sorted_src,
                                                       const float* __restrict__ a_s,
                                                       const float* __restrict__ a_d,
                                                       float* __restrict__ edge_w) {
    int is64 = detect_is64((const int*)ei);
    int e = blockIdx.x * 256 + threadIdx.x;
    if (e < N_EDGES) {
        int dst = edge_at(ei, is64, (long long)N_EDGES + e);
        int src = edge_at(ei, is64, e);
        int pos = offsets[dst] + atomicAdd(&cursor[dst], 1);
        sorted_src[pos] = src;
        float4 as4 = *(const float4*)&a_s[src * 4];
        float4 ad4 = *(const float4*)&a_d[dst * 4];
        float4 w;
        w.x = __expf(leaky(as4.x + ad4.x));
        w.y = __expf(leaky(as4.y + ad4.y));
        w.z = __expf(leaky(as4.z + ad4.z));
        w.w = __expf(leaky(as4.w + ad4.w));
        *(float4*)&edge_w[(size_t)pos * 4] = w;
    }
}

// ---------------- K5: segment softmax + weighted gather ----------------
// 2 waves per node (alternating 4-edge chunks), partials combined via LDS.
// No max subtraction (logits bounded ~|8|; fp32 exp safe; algebraically identical).
__global__ __launch_bounds__(256) void gather_kernel(const unsigned short* __restrict__ xlb,
                                                     const float* __restrict__ a_s,
                                                     const float* __restrict__ a_d,
                                                     const int* __restrict__ offsets,
                                                     const int* __restrict__ sorted_src,
                                                     const float* __restrict__ edge_w,
                                                     const float* __restrict__ bias,
                                                     float* __restrict__ out) {
    __shared__ float cl[2][64][9];
    int wv = threadIdx.x >> 6;
    int nib = wv >> 1;
    int sub = wv & 1;
    int node = blockIdx.x * 2 + nib;    // grid = N_NODES/2
    int lane = threadIdx.x & 63;
    int hd = lane >> 4;
    int beg = offsets[node], end = offsets[node + 1];

    const unsigned short* xrow = xlb + lane * 8;
    float acc[8] = {0, 0, 0, 0, 0, 0, 0, 0};
    float denom = 0.f;

    if (sub == 0) {   // self-loop
        float4 as4 = *(const float4*)&a_s[node * 4];
        float4 ad4 = *(const float4*)&a_d[node * 4];
        float4 ws;
        ws.x = __expf(leaky(as4.x + ad4.x));
        ws.y = __expf(leaky(as4.y + ad4.y));
        ws.z = __expf(leaky(as4.z + ad4.z));
        ws.w = __expf(leaky(as4.w + ad4.w));
        float w = sel_head(ws, hd);
        denom = w;
        uint4 r = *(const uint4*)(xrow + (size_t)node * HC);
        float f[8];
        bf8_decode(r, f);
        #pragma unroll
        for (int k = 0; k < 8; k++) acc[k] = w * f[k];
    }

    for (int c0 = beg + sub * 4; c0 < end; c0 += 8) {
        int n = end - c0;
        if (n >= 4) {
            int s0 = sorted_src[c0];
            int s1 = sorted_src[c0 + 1];
            int s2 = sorted_src[c0 + 2];
            int s3 = sorted_src[c0 + 3];
            uint4 r0 = *(const uint4*)(xrow + (size_t)s0 * HC);
            uint4 r1 = *(const uint4*)(xrow + (size_t)s1 * HC);
            uint4 r2 = *(const uint4*)(xrow + (size_t)s2 * HC);
            uint4 r3 = *(const uint4*)(xrow + (size_t)s3 * HC);
            float4 wa = *(const float4*)&edge_w[(size_t)c0 * 4];
            float4 wb = *(const float4*)&edge_w[(size_t)(c0 + 1) * 4];
            float4 wc = *(const float4*)&edge_w[(size_t)(c0 + 2) * 4];
            float4 wd = *(const float4*)&edge_w[(size_t)(c0 + 3) * 4];
            float w0 = sel_head(wa, hd), w1 = sel_head(wb, hd);
            float w2 = sel_head(wc, hd), w3 = sel_head(wd, hd);
            denom += (w0 + w1) + (w2 + w3);
            float f0[8], f1[8], f2[8], f3[8];
            bf8_decode(r0, f0);
            bf8_decode(r1, f1);
            bf8_decode(r2, f2);
            bf8_decode(r3, f3);
            #pragma unroll
            for (int k = 0; k < 8; k++)
                acc[k] += (w0 * f0[k] + w1 * f1[k]) + (w2 * f2[k] + w3 * f3[k]);
        } else {
            for (int j = 0; j < n; j++) {
                int s0 = sorted_src[c0 + j];
                uint4 r0 = *(const uint4*)(xrow + (size_t)s0 * HC);
                float4 wa = *(const float4*)&edge_w[(size_t)(c0 + j) * 4];
                float w0 = sel_head(wa, hd);
                denom += w0;
                float f0[8];
                bf8_decode(r0, f0);
                #pragma unroll
                for (int k = 0; k < 8; k++) acc[k] += w0 * f0[k];
            }
        }
    }

    if (sub == 1) {
        #pragma unroll
        for (int k = 0; k < 8; k++) cl[nib][lane][k] = acc[k];
        cl[nib][lane][8] = denom;
    }
    __syncthreads();
    if (sub == 0) {
        #pragma unroll
        for (int k = 0; k < 8; k++) acc[k] += cl[nib][lane][k];
        denom += cl[nib][lane][8];

        float rd = 0.25f / (denom + 1e-16f);
        float v[8];
        #pragma unroll
        for (int k = 0; k < 8; k++) {
            float t = acc[k] * rd;
            t += __shfl_xor(t, 16, 64);
            t += __shfl_xor(t, 32, 64);
            v[k] = t;
        }
        if (hd == 0) {
            float4 b0 = *(const float4*)&bias[lane * 8];
            float4 b1 = *(const float4*)&bias[lane * 8 + 4];
            float o[8];
            o[0] = v[0] + b0.x; o[1] = v[1] + b0.y; o[2] = v[2] + b0.z; o[3] = v[3] + b0.w;
            o[4] = v[4] + b1.x; o[5] = v[5] + b1.y; o[6] = v[6] + b1.z; o[7] = v[7] + b1.w;
            #pragma unroll
            for (int k = 0; k < 8; k++) o[k] = o[k] > 0.f ? o[k] : expm1f(o[k]);
            *(float4*)&out[(size_t)node * OUT_CH + lane * 8]     = make_float4(o[0], o[1], o[2], o[3]);
            *(float4*)&out[(size_t)node * OUT_CH + lane * 8 + 4] = make_float4(o[4], o[5], o[6], o[7]);
        }
    }
}

// ---------------- launch ----------------
extern "C" void kernel_launch(void* const* d_in, const int* in_sizes, int n_in,
                              void* d_out, int out_size, void* d_ws, size_t ws_size,
                              hipStream_t stream) {
    const float* x       = (const float*)d_in[0];
    const float* W       = (const float*)d_in[1];
    const float* att_src = (const float*)d_in[2];
    const float* att_dst = (const float*)d_in[3];
    const float* bias    = (const float*)d_in[4];
    const void*  ei      = d_in[5];
    float* out = (float*)d_out;

    char* ws = (char*)d_ws;
    size_t off = 0;
    unsigned short* xlb = (unsigned short*)(ws + off); off += (size_t)N_PAD64 * HC * sizeof(unsigned short);
    float* a_s     = (float*)(ws + off); off += (size_t)N_NODES * HEADS * sizeof(float);
    float* a_d     = (float*)(ws + off); off += (size_t)N_NODES * HEADS * sizeof(float);
    int* counts    = (int*)(ws + off);   off += (size_t)N_NODES * sizeof(int);
    int* cursor    = (int*)(ws + off);   off += (size_t)N_NODES * sizeof(int);   // contiguous with counts
    int* offsets   = (int*)(ws + off);   off += (size_t)(N_NODES + 1) * sizeof(int);
    off = (off + 15) & ~(size_t)15;
    int* sorted_src = (int*)(ws + off);  off += (size_t)N_EDGES * sizeof(int);
    off = (off + 15) & ~(size_t)15;
    float* edge_w  = (float*)(ws + off); off += (size_t)N_EDGES * HEADS * sizeof(float);
    unsigned short* Wt = (unsigned short*)(ws + off); off += (size_t)IN_CH * HC * sizeof(unsigned short);

    hipMemsetAsync(counts, 0, 2u * N_NODES * sizeof(int), stream);   // counts + cursor
    fusedA_kernel<<<CVW_BLOCKS + CNT_BLOCKS, 256, 0, stream>>>(W, Wt, ei, counts);
    gemm_kernel<<<GRID_M, 512, 0, stream>>>(x, Wt, xlb, att_src, att_dst, a_s, a_d);
    scan_kernel<<<1, 1024, 0, stream>>>(counts, offsets);
    scatterw_kernel<<<(N_EDGES + 255) / 256, 256, 0, stream>>>(ei, offsets, cursor, sorted_src, a_s, a_d, edge_w);
    gather_kernel<<<N_NODES / 2, 256, 0, stream>>>(xlb, a_s, a_d, offsets, sorted_src, edge_w, bias, out);
}